// Round 4
// baseline (150.547 us; speedup 1.0000x reference)
//
#include <hip/hip_runtime.h>

#define KINST 64

__device__ __forceinline__ float bcastf(float v, int l) {
  return __int_as_float(__builtin_amdgcn_readlane(__float_as_int(v), l));
}

// ---------------------------------------------------------------------------
// Pass 1: per-(b,k) sums of prediction and pixel counts + k0 cache.
// sums layout: [B][K][4] = {sum_x, sum_y, sum_z, count}
// k0c: per-pixel instance slot (0..63, 64 = no palette match), u8. May be null.
// LDS accumulators: ls[wave][component][k] -> atomic bank = k%32 (2-way, free).
// ---------------------------------------------------------------------------
__global__ __launch_bounds__(256) void k_stats(const float* __restrict__ pred,
                                               const float* __restrict__ targ,
                                               const int* __restrict__ pal,
                                               float* __restrict__ sums,
                                               unsigned char* __restrict__ k0c,
                                               int HW) {
  int b = blockIdx.y;
  __shared__ float ls[4][4][KINST];  // [wave][component][k]
  __shared__ int pal_s[KINST];
  for (int i = threadIdx.x; i < 4 * 4 * KINST; i += blockDim.x)
    (&ls[0][0][0])[i] = 0.f;
  for (int i = threadIdx.x; i < KINST; i += blockDim.x) pal_s[i] = pal[i];
  __syncthreads();
  int w = threadIdx.x >> 6;
  const float* tb = targ + (size_t)b * 3 * HW;
  const float* pb = pred + (size_t)b * 3 * HW;
  unsigned char* kb = k0c ? k0c + (size_t)b * HW : nullptr;
  for (int i = blockIdx.x * blockDim.x + threadIdx.x; i < HW;
       i += gridDim.x * blockDim.x) {
    float t0 = tb[i], t1 = tb[i + HW], t2 = tb[i + 2 * HW];
    int pid = (int)(fmaf(t0, 65536.f, fmaf(t1, 256.f, t2)) + 0.5f);
    int k0 = -1;
    if (pid >= 0 && pid < KINST && pal_s[pid] == pid) k0 = pid;  // fast path
    else {
      for (int j = 0; j < KINST; ++j)
        if (pal_s[j] == pid) { k0 = j; break; }
    }
    if (kb) kb[i] = (unsigned char)(k0 < 0 ? KINST : k0);
    if (k0 < 0) continue;
    atomicAdd(&ls[w][0][k0], pb[i]);
    atomicAdd(&ls[w][1][k0], pb[i + HW]);
    atomicAdd(&ls[w][2][k0], pb[i + 2 * HW]);
    atomicAdd(&ls[w][3][k0], 1.f);
  }
  __syncthreads();
  // finalize: thread i handles (component c, instance k); sums stay [k][4]
  for (int i = threadIdx.x; i < 4 * KINST; i += blockDim.x) {
    int c = i >> 6, k = i & 63;
    float v = ls[0][c][k] + ls[1][c][k] + ls[2][c][k] + ls[3][c][k];
    atomicAdd(&sums[((size_t)b * KINST + k) * 4 + c], v);
  }
}

// ---------------------------------------------------------------------------
// Pass 2 (grid = B): per-(b,k) derived quantities + combined inter weights.
// prep layout: [B][K][12] =
//   {mean0,mean1,mean2, unused, meanz0,meanz1,meanz2, f_intra, scale, cf, 0,0}
// cwT_g layout: [B][65][64]; cwT_g[b][k0][k] = (k==k0||k0==64)?0
//                                             : 300*dw[k*K+k0]*scale[b][k]
// ---------------------------------------------------------------------------
__global__ void k_prep(const float* __restrict__ sums, const int* __restrict__ pal,
                       const unsigned char* __restrict__ nb_raw,
                       const float* __restrict__ dw,
                       float* __restrict__ prep, float* __restrict__ cwT_g,
                       int HW, int K) {
  int b = blockIdx.x;
  __shared__ float scale_sh[KINST];
  int k = threadIdx.x;
  if (k < KINST) {
    bool nb = (nb_raw[b] != 0) || (nb_raw[4 * b] != 0);  // robust bool width
    const float* s = sums + ((size_t)b * KINST + k) * 4;
    float cnt = s[3];
    float inv = cnt > 0.f ? 1.f / cnt : 0.f;
    float m0 = s[0] * inv, m1 = s[1] * inv, m2 = s[2] * inv;
    bool isbg = (pal[k] == 0);
    float cf = (!isbg || !nb) ? 1.f : 0.f;
    float sc = (!isbg && cnt > 0.f) ? 10.f / (((float)HW - cnt) * sqrtf(cnt)) : 0.f;
    float* o = prep + ((size_t)b * KINST + k) * 12;
    o[0] = m0; o[1] = m1; o[2] = m2;
    o[3] = 0.f;
    o[4] = isbg ? 0.f : m0;
    o[5] = isbg ? 0.f : m1;
    o[6] = isbg ? 0.f : m2;
    o[7] = cnt > 0.f ? cf / (3.f * cnt) : 0.f;
    o[8] = sc; o[9] = cf; o[10] = 0.f; o[11] = 0.f;
    scale_sh[k] = sc;
  }
  __syncthreads();
  float* ct = cwT_g + (size_t)b * 65 * KINST;
  for (int t = threadIdx.x; t < 65 * KINST; t += blockDim.x) {
    int k0 = t >> 6, kk = t & 63;
    float v = 0.f;
    if (k0 < KINST && kk != k0) v = 300.f * dw[kk * K + k0] * scale_sh[kk];
    ct[t] = v;
  }
}

// ---------------------------------------------------------------------------
// Pass 3 (hot): lane = instance k. Pixel broadcast via wave-uniform GLOBAL
// loads (one L1 transaction broadcast, VMEM pipe) instead of VALU readlanes.
// Per j: 3 uniform loads + 3 sub + 3 fma + rcp + acc-fma + 1 conflict-free
// ds_read + 1 k0 readlane.
// res layout: [B][2] = {intra, inter}
// ---------------------------------------------------------------------------
template <bool USE_CACHE>
__global__ __launch_bounds__(256) void k_pix(const float* __restrict__ pred,
                                             const float* __restrict__ targ,
                                             const unsigned char* __restrict__ k0c,
                                             const int* __restrict__ pal,
                                             const float* __restrict__ prep,
                                             const float* __restrict__ cwT_g,
                                             float* __restrict__ res, int HW) {
  int b = blockIdx.y;
  __shared__ float cwT[65][KINST];
  __shared__ float4 Z_s[65];
  __shared__ int pal_s[KINST];
  {
    const float4* src = (const float4*)(cwT_g + (size_t)b * 65 * KINST);
    float4* dst = (float4*)&cwT[0][0];
    for (int i = threadIdx.x; i < 65 * (KINST / 4); i += blockDim.x) dst[i] = src[i];
    for (int i = threadIdx.x; i < KINST; i += blockDim.x) {
      const float* p = prep + ((size_t)b * KINST + i) * 12;
      Z_s[i] = make_float4(p[4], p[5], p[6], p[7]);
      if (!USE_CACHE) pal_s[i] = pal[i];
    }
    if (threadIdx.x == 0) Z_s[KINST] = make_float4(0.f, 0.f, 0.f, 0.f);
  }
  __syncthreads();
  int lane = threadIdx.x & 63;
  const float* pm = prep + ((size_t)b * KINST + lane) * 12;
  float a0 = pm[0], a1 = pm[1], a2 = pm[2];  // this lane's instance mean (raw)
  const float* pb = pred + (size_t)b * 3 * HW;
  const float* tb = targ + (size_t)b * 3 * HW;
  const unsigned char* kb = USE_CACHE ? k0c + (size_t)b * HW : nullptr;
  float acc_intra = 0.f, acc_inter = 0.f;
  int gw = blockIdx.x * (blockDim.x >> 6) + (threadIdx.x >> 6);
  int nw = gridDim.x * (blockDim.x >> 6);
  for (int base = gw * 64; base < HW; base += nw * 64) {
    int i = base + lane;
    float p0 = 0.f, p1 = 0.f, p2 = 0.f;
    int k0 = KINST;
    if (i < HW) {
      p0 = pb[i]; p1 = pb[i + HW]; p2 = pb[i + 2 * HW];
      if (USE_CACHE) {
        k0 = kb[i];
      } else {
        float t0 = tb[i], t1 = tb[i + HW], t2 = tb[i + 2 * HW];
        int pid = (int)(fmaf(t0, 65536.f, fmaf(t1, 256.f, t2)) + 0.5f);
        k0 = KINST;
        if (pid >= 0 && pid < KINST && pal_s[pid] == pid) k0 = pid;
        else {
          for (int j = 0; j < KINST; ++j)
            if (pal_s[j] == pid) { k0 = j; break; }
        }
      }
    }
    // intra: huber toward own (bg-zeroed) mean; f_intra folds cf/(3*cnt)
    float4 z = Z_s[k0];
    float q0 = fabsf(p0 - z.x), q1 = fabsf(p1 - z.y), q2 = fabsf(p2 - z.z);
    float hp = (q0 < 1.f ? 0.5f * q0 * q0 : q0 - 0.5f) +
               (q1 < 1.f ? 0.5f * q1 * q1 : q1 - 0.5f) +
               (q2 < 1.f ? 0.5f * q2 * q2 : q2 - 0.5f);
    acc_intra = fmaf(hp, z.w, acc_intra);
    if (base + 64 <= HW) {
      // inter fast path: wave-uniform loads broadcast pixel j to all lanes
      #pragma unroll 8
      for (int j = 0; j < 64; ++j) {
        float sp0 = pb[base + j];
        float sp1 = pb[base + j + HW];
        float sp2 = pb[base + j + 2 * HW];
        int sk = __builtin_amdgcn_readlane(k0, j);
        float c = cwT[sk][lane];  // uniform row, lane-consecutive: no conflict
        float dx = sp0 - a0, dy = sp1 - a1, dz = sp2 - a2;
        float arg = fmaf(dz, dz, fmaf(dy, dy, fmaf(dx, dx, 1.f)));
        acc_inter = fmaf(__builtin_amdgcn_rcpf(arg), c, acc_inter);
      }
    } else {
      // tail path (HW % 64 != 0 only): readlane broadcasts of lane-held pixel
      #pragma unroll 8
      for (int j = 0; j < 64; ++j) {
        float sp0 = bcastf(p0, j), sp1 = bcastf(p1, j), sp2 = bcastf(p2, j);
        int sk = __builtin_amdgcn_readlane(k0, j);
        float c = cwT[sk][lane];  // sk==KINST row is zero for invalid pixels
        float dx = sp0 - a0, dy = sp1 - a1, dz = sp2 - a2;
        float arg = fmaf(dz, dz, fmaf(dy, dy, fmaf(dx, dx, 1.f)));
        acc_inter = fmaf(__builtin_amdgcn_rcpf(arg), c, acc_inter);
      }
    }
  }
  for (int o = 32; o > 0; o >>= 1) {
    acc_intra += __shfl_down(acc_intra, o, 64);
    acc_inter += __shfl_down(acc_inter, o, 64);
  }
  __shared__ float rA[4], rB[4];
  int wid = threadIdx.x >> 6;
  if ((threadIdx.x & 63) == 0) { rA[wid] = acc_intra; rB[wid] = acc_inter; }
  __syncthreads();
  if (threadIdx.x == 0) {
    float a = 0.f, c = 0.f;
    int nwv = blockDim.x >> 6;
    for (int i = 0; i < nwv; ++i) { a += rA[i]; c += rB[i]; }
    atomicAdd(&res[b * 2 + 0], a);
    atomicAdd(&res[b * 2 + 1], c);
  }
}

// ---------------------------------------------------------------------------
// Pass 4: single block; pairwise mean repulsion per b + final combine.
// ---------------------------------------------------------------------------
__global__ __launch_bounds__(256) void k_final(const float* __restrict__ prep,
                                               const float* __restrict__ dw,
                                               const float* __restrict__ res,
                                               float* __restrict__ out, int B, int K) {
  __shared__ float rA[4], rB[4], rC[4];
  float total = 0.f;  // accumulated by thread 0
  for (int b = 0; b < B; ++b) {
    const float* pb = prep + (size_t)b * K * 12;
    float psum = 0.f, pcnt = 0.f, cfs = 0.f;
    for (int idx = threadIdx.x; idx < K * K; idx += blockDim.x) {
      int j = idx >> 6, k = idx & 63;
      if (j < k) {
        float m = pb[j * 12 + 9] * pb[k * 12 + 9];
        float d0 = pb[j * 12 + 4] - pb[k * 12 + 4];
        float d1 = pb[j * 12 + 5] - pb[k * 12 + 5];
        float d2 = pb[j * 12 + 6] - pb[k * 12 + 6];
        float sqd = d0 * d0 + d1 * d1 + d2 * d2;
        psum += dw[j * K + k] * 300.f / (sqd + 1.f) * m;
        pcnt += m;
      }
    }
    for (int k = threadIdx.x; k < K; k += blockDim.x) cfs += pb[k * 12 + 9];
    for (int o = 32; o > 0; o >>= 1) {
      psum += __shfl_down(psum, o, 64);
      pcnt += __shfl_down(pcnt, o, 64);
      cfs += __shfl_down(cfs, o, 64);
    }
    int wid = threadIdx.x >> 6;
    __syncthreads();  // protect rA/rB/rC reuse across b iterations
    if ((threadIdx.x & 63) == 0) { rA[wid] = psum; rB[wid] = pcnt; rC[wid] = cfs; }
    __syncthreads();
    if (threadIdx.x == 0) {
      float ps = 0.f, pc = 0.f, cs = 0.f;
      for (int i = 0; i < 4; ++i) { ps += rA[i]; pc += rB[i]; cs += rC[i]; }
      float mean_sep = pc > 0.f ? ps / fmaxf(pc, 1.f) : 0.f;
      float ct = fmaxf(cs, 1.f);
      total += (res[b * 2 + 0] + res[b * 2 + 1] + mean_sep) / ct;
    }
  }
  if (threadIdx.x == 0) out[0] = total / (float)B;
}

extern "C" void kernel_launch(void* const* d_in, const int* in_sizes, int n_in,
                              void* d_out, int out_size, void* d_ws, size_t ws_size,
                              hipStream_t stream) {
  const float* pred = (const float*)d_in[0];
  const float* targ = (const float*)d_in[1];
  const unsigned char* nb = (const unsigned char*)d_in[2];
  const float* dw = (const float*)d_in[3];
  const int* pal = (const int*)d_in[4];
  int B = in_sizes[2];                 // 4
  int K = in_sizes[4];                 // 64 (kernels assume KINST==64)
  int HW = in_sizes[0] / (3 * B);      // 262144

  // ws layout (floats): sums[B*K*4] | res[B*2] | prep[B*K*12] | cwT_g[B*65*64]
  // then (bytes): k0c[B*HW] if it fits
  float* sums = (float*)d_ws;
  float* res = sums + (size_t)B * K * 4;
  float* prep = res + (size_t)B * 2;
  float* cwT_g = prep + (size_t)B * K * 12;
  size_t base_floats = (size_t)B * K * 4 + (size_t)B * 2 + (size_t)B * K * 12 +
                       (size_t)B * 65 * KINST;
  unsigned char* k0c = (unsigned char*)(cwT_g + (size_t)B * 65 * KINST);
  bool use_cache = ws_size >= base_floats * 4 + (size_t)B * HW;
  if (!use_cache) k0c = nullptr;

  hipMemsetAsync(d_ws, 0, ((size_t)B * K * 4 + (size_t)B * 2) * sizeof(float), stream);
  k_stats<<<dim3(256, B), 256, 0, stream>>>(pred, targ, pal, sums, k0c, HW);
  k_prep<<<B, 256, 0, stream>>>(sums, pal, nb, dw, prep, cwT_g, HW, K);
  if (use_cache)
    k_pix<true><<<dim3(512, B), 256, 0, stream>>>(pred, targ, k0c, pal, prep, cwT_g, res, HW);
  else
    k_pix<false><<<dim3(512, B), 256, 0, stream>>>(pred, targ, k0c, pal, prep, cwT_g, res, HW);
  k_final<<<1, 256, 0, stream>>>(prep, dw, res, (float*)d_out, B, K);
}

// Round 5
// 147.688 us; speedup vs baseline: 1.0194x; 1.0194x over previous
//
#include <hip/hip_runtime.h>

#define KINST 64

__device__ __forceinline__ int decode_k0(float t0, float t1, float t2,
                                         const int* pal_s) {
  int pid = (int)(fmaf(t0, 65536.f, fmaf(t1, 256.f, t2)) + 0.5f);
  if (pid >= 0 && pid < KINST && pal_s[pid] == pid) return pid;  // fast path
  for (int j = 0; j < KINST; ++j)
    if (pal_s[j] == pid) return j;
  return KINST;  // no palette match
}

// ---------------------------------------------------------------------------
// Pass 1: per-(b,k) sums of prediction and pixel counts + k0 cache.
// float4 path: 4 pixels/thread. LDS accumulators ls[wave][component][k]:
// within one atomic instr all lanes hit banks k%32 (2-way worst aliasing).
// sums layout: [B][K][4] = {sum_x, sum_y, sum_z, count}
// ---------------------------------------------------------------------------
__global__ __launch_bounds__(256) void k_stats(const float* __restrict__ pred,
                                               const float* __restrict__ targ,
                                               const int* __restrict__ pal,
                                               float* __restrict__ sums,
                                               unsigned char* __restrict__ k0c,
                                               int HW) {
  int b = blockIdx.y;
  __shared__ float ls[4][4][KINST];  // [wave][component][k]
  __shared__ int pal_s[KINST];
  for (int i = threadIdx.x; i < 4 * 4 * KINST; i += blockDim.x)
    (&ls[0][0][0])[i] = 0.f;
  for (int i = threadIdx.x; i < KINST; i += blockDim.x) pal_s[i] = pal[i];
  __syncthreads();
  int w = threadIdx.x >> 6;
  const float* tb = targ + (size_t)b * 3 * HW;
  const float* pb = pred + (size_t)b * 3 * HW;
  unsigned char* kb = k0c ? k0c + (size_t)b * HW : nullptr;
  int nq = HW >> 2;
  const float4* tb4 = (const float4*)tb;
  const float4* pb4 = (const float4*)pb;
  for (int q = blockIdx.x * blockDim.x + threadIdx.x; q < nq;
       q += gridDim.x * blockDim.x) {
    float4 t0 = tb4[q], t1 = tb4[q + nq], t2 = tb4[q + 2 * nq];
    float4 p0 = pb4[q], p1 = pb4[q + nq], p2 = pb4[q + 2 * nq];
    int ka = decode_k0(t0.x, t1.x, t2.x, pal_s);
    int kc = decode_k0(t0.y, t1.y, t2.y, pal_s);
    int kd = decode_k0(t0.z, t1.z, t2.z, pal_s);
    int ke = decode_k0(t0.w, t1.w, t2.w, pal_s);
    if (ka < KINST) {
      atomicAdd(&ls[w][0][ka], p0.x); atomicAdd(&ls[w][1][ka], p1.x);
      atomicAdd(&ls[w][2][ka], p2.x); atomicAdd(&ls[w][3][ka], 1.f);
    }
    if (kc < KINST) {
      atomicAdd(&ls[w][0][kc], p0.y); atomicAdd(&ls[w][1][kc], p1.y);
      atomicAdd(&ls[w][2][kc], p2.y); atomicAdd(&ls[w][3][kc], 1.f);
    }
    if (kd < KINST) {
      atomicAdd(&ls[w][0][kd], p0.z); atomicAdd(&ls[w][1][kd], p1.z);
      atomicAdd(&ls[w][2][kd], p2.z); atomicAdd(&ls[w][3][kd], 1.f);
    }
    if (ke < KINST) {
      atomicAdd(&ls[w][0][ke], p0.w); atomicAdd(&ls[w][1][ke], p1.w);
      atomicAdd(&ls[w][2][ke], p2.w); atomicAdd(&ls[w][3][ke], 1.f);
    }
    if (kb) {
      uchar4 kk = make_uchar4((unsigned char)ka, (unsigned char)kc,
                              (unsigned char)kd, (unsigned char)ke);
      *(uchar4*)(kb + 4 * (size_t)q) = kk;
    }
  }
  // scalar tail (HW % 4 != 0 only)
  for (int i = (nq << 2) + blockIdx.x * blockDim.x + threadIdx.x; i < HW;
       i += gridDim.x * blockDim.x) {
    int k0 = decode_k0(tb[i], tb[i + HW], tb[i + 2 * HW], pal_s);
    if (kb) kb[i] = (unsigned char)k0;
    if (k0 < KINST) {
      atomicAdd(&ls[w][0][k0], pb[i]); atomicAdd(&ls[w][1][k0], pb[i + HW]);
      atomicAdd(&ls[w][2][k0], pb[i + 2 * HW]); atomicAdd(&ls[w][3][k0], 1.f);
    }
  }
  __syncthreads();
  for (int i = threadIdx.x; i < 4 * KINST; i += blockDim.x) {
    int c = i >> 6, k = i & 63;
    float v = ls[0][c][k] + ls[1][c][k] + ls[2][c][k] + ls[3][c][k];
    atomicAdd(&sums[((size_t)b * KINST + k) * 4 + c], v);
  }
}

// ---------------------------------------------------------------------------
// Pass 2 (grid = B): per-(b,k) derived quantities + combined inter weights.
// prep layout: [B][K][12] =
//   {na0,na1,na2, m2, meanz0,meanz1,meanz2, f_intra, scale, cf, 0,0}
//   where na = -2*mean (raw), m2 = |mean|^2.
// cwT_g layout: [B][65][64]; cwT_g[b][k0][k] = (k==k0||k0==64)?0
//                                             : 300*dw[k*K+k0]*scale[b][k]
// ---------------------------------------------------------------------------
__global__ void k_prep(const float* __restrict__ sums, const int* __restrict__ pal,
                       const unsigned char* __restrict__ nb_raw,
                       const float* __restrict__ dw,
                       float* __restrict__ prep, float* __restrict__ cwT_g,
                       int HW, int K) {
  int b = blockIdx.x;
  __shared__ float scale_sh[KINST];
  int k = threadIdx.x;
  if (k < KINST) {
    bool nb = (nb_raw[b] != 0) || (nb_raw[4 * b] != 0);  // robust bool width
    const float* s = sums + ((size_t)b * KINST + k) * 4;
    float cnt = s[3];
    float inv = cnt > 0.f ? 1.f / cnt : 0.f;
    float m0 = s[0] * inv, m1 = s[1] * inv, m2 = s[2] * inv;
    bool isbg = (pal[k] == 0);
    float cf = (!isbg || !nb) ? 1.f : 0.f;
    float sc = (!isbg && cnt > 0.f) ? 10.f / (((float)HW - cnt) * sqrtf(cnt)) : 0.f;
    float* o = prep + ((size_t)b * KINST + k) * 12;
    o[0] = -2.f * m0; o[1] = -2.f * m1; o[2] = -2.f * m2;
    o[3] = m0 * m0 + m1 * m1 + m2 * m2;
    o[4] = isbg ? 0.f : m0;
    o[5] = isbg ? 0.f : m1;
    o[6] = isbg ? 0.f : m2;
    o[7] = cnt > 0.f ? cf / (3.f * cnt) : 0.f;
    o[8] = sc; o[9] = cf; o[10] = 0.f; o[11] = 0.f;
    scale_sh[k] = sc;
  }
  __syncthreads();
  float* ct = cwT_g + (size_t)b * 65 * KINST;
  for (int t = threadIdx.x; t < 65 * KINST; t += blockDim.x) {
    int k0 = t >> 6, kk = t & 63;
    float v = 0.f;
    if (k0 < KINST && kk != k0) v = 300.f * dw[kk * K + k0] * scale_sh[kk];
    ct[t] = v;
  }
}

// ---------------------------------------------------------------------------
// Pass 3 (hot): lane = instance k. Per 64-pixel batch, each lane stages its
// pixel record (p0,p1,p2,P2+1) into a wave-private LDS array; the j-loop
// broadcasts via uniform-address ds_read_b128 (conflict-free, immediate
// offsets). Only k0 uses a readlane. arg = 1+d2 via 3-fma refold.
// res layout: [B][2] = {intra, inter}
// ---------------------------------------------------------------------------
template <bool USE_CACHE>
__global__ __launch_bounds__(256) void k_pix(const float* __restrict__ pred,
                                             const float* __restrict__ targ,
                                             const unsigned char* __restrict__ k0c,
                                             const int* __restrict__ pal,
                                             const float* __restrict__ prep,
                                             const float* __restrict__ cwT_g,
                                             float* __restrict__ res, int HW) {
  int b = blockIdx.y;
  __shared__ float cwT[65][KINST];
  __shared__ float4 Z_s[65];
  __shared__ float4 rec[4][64];  // per-wave pixel records
  __shared__ int pal_s[KINST];
  {
    const float4* src = (const float4*)(cwT_g + (size_t)b * 65 * KINST);
    float4* dst = (float4*)&cwT[0][0];
    for (int i = threadIdx.x; i < 65 * (KINST / 4); i += blockDim.x) dst[i] = src[i];
    for (int i = threadIdx.x; i < KINST; i += blockDim.x) {
      const float* p = prep + ((size_t)b * KINST + i) * 12;
      Z_s[i] = make_float4(p[4], p[5], p[6], p[7]);
      if (!USE_CACHE) pal_s[i] = pal[i];
    }
    if (threadIdx.x == 0) Z_s[KINST] = make_float4(0.f, 0.f, 0.f, 0.f);
  }
  __syncthreads();
  int lane = threadIdx.x & 63;
  int wid = threadIdx.x >> 6;
  const float* pm = prep + ((size_t)b * KINST + lane) * 12;
  float na0 = pm[0], na1 = pm[1], na2 = pm[2], m2c = pm[3];
  const float* pb = pred + (size_t)b * 3 * HW;
  const float* tb = targ + (size_t)b * 3 * HW;
  const unsigned char* kb = USE_CACHE ? k0c + (size_t)b * HW : nullptr;
  float acc_intra = 0.f, acc_inter = 0.f;
  int gw = blockIdx.x * (blockDim.x >> 6) + wid;
  int nw = gridDim.x * (blockDim.x >> 6);
  for (int base = gw * 64; base < HW; base += nw * 64) {
    int i = base + lane;
    float p0 = 0.f, p1 = 0.f, p2 = 0.f;
    int k0 = KINST;
    if (i < HW) {
      p0 = pb[i]; p1 = pb[i + HW]; p2 = pb[i + 2 * HW];
      if (USE_CACHE) k0 = kb[i];
      else k0 = decode_k0(tb[i], tb[i + HW], tb[i + 2 * HW], pal_s);
    }
    // intra: huber toward own (bg-zeroed) mean; f_intra folds cf/(3*cnt)
    float4 z = Z_s[k0];
    float q0 = fabsf(p0 - z.x), q1 = fabsf(p1 - z.y), q2 = fabsf(p2 - z.z);
    float hp = (q0 < 1.f ? 0.5f * q0 * q0 : q0 - 0.5f) +
               (q1 < 1.f ? 0.5f * q1 * q1 : q1 - 0.5f) +
               (q2 < 1.f ? 0.5f * q2 * q2 : q2 - 0.5f);
    acc_intra = fmaf(hp, z.w, acc_intra);
    // stage this wave's 64 pixel records (record: p0,p1,p2, 1+|P|^2)
    float P2p = fmaf(p0, p0, fmaf(p1, p1, fmaf(p2, p2, 1.f)));
    rec[wid][lane] = make_float4(p0, p1, p2, P2p);
    // inter: 64 instances across lanes; uniform-address LDS broadcast per j
    #pragma unroll 8
    for (int j = 0; j < 64; ++j) {
      float4 r = rec[wid][j];  // uniform addr -> broadcast, conflict-free
      int sk = __builtin_amdgcn_readlane(k0, j);
      float c = cwT[sk][lane];  // uniform row, lane-consecutive: no conflict
      float arg = fmaf(r.x, na0, fmaf(r.y, na1, fmaf(r.z, na2, r.w + m2c)));
      acc_inter = fmaf(__builtin_amdgcn_rcpf(arg), c, acc_inter);
    }
  }
  for (int o = 32; o > 0; o >>= 1) {
    acc_intra += __shfl_down(acc_intra, o, 64);
    acc_inter += __shfl_down(acc_inter, o, 64);
  }
  __shared__ float rA[4], rB[4];
  if ((threadIdx.x & 63) == 0) { rA[wid] = acc_intra; rB[wid] = acc_inter; }
  __syncthreads();
  if (threadIdx.x == 0) {
    float a = 0.f, c = 0.f;
    int nwv = blockDim.x >> 6;
    for (int i = 0; i < nwv; ++i) { a += rA[i]; c += rB[i]; }
    atomicAdd(&res[b * 2 + 0], a);
    atomicAdd(&res[b * 2 + 1], c);
  }
}

// ---------------------------------------------------------------------------
// Pass 4: single block; pairwise mean repulsion per b + final combine.
// ---------------------------------------------------------------------------
__global__ __launch_bounds__(256) void k_final(const float* __restrict__ prep,
                                               const float* __restrict__ dw,
                                               const float* __restrict__ res,
                                               float* __restrict__ out, int B, int K) {
  __shared__ float rA[4], rB[4], rC[4];
  float total = 0.f;  // accumulated by thread 0
  for (int b = 0; b < B; ++b) {
    const float* pb = prep + (size_t)b * K * 12;
    float psum = 0.f, pcnt = 0.f, cfs = 0.f;
    for (int idx = threadIdx.x; idx < K * K; idx += blockDim.x) {
      int j = idx >> 6, k = idx & 63;
      if (j < k) {
        float m = pb[j * 12 + 9] * pb[k * 12 + 9];
        float d0 = pb[j * 12 + 4] - pb[k * 12 + 4];
        float d1 = pb[j * 12 + 5] - pb[k * 12 + 5];
        float d2 = pb[j * 12 + 6] - pb[k * 12 + 6];
        float sqd = d0 * d0 + d1 * d1 + d2 * d2;
        psum += dw[j * K + k] * 300.f / (sqd + 1.f) * m;
        pcnt += m;
      }
    }
    for (int k = threadIdx.x; k < K; k += blockDim.x) cfs += pb[k * 12 + 9];
    for (int o = 32; o > 0; o >>= 1) {
      psum += __shfl_down(psum, o, 64);
      pcnt += __shfl_down(pcnt, o, 64);
      cfs += __shfl_down(cfs, o, 64);
    }
    int wid = threadIdx.x >> 6;
    __syncthreads();  // protect rA/rB/rC reuse across b iterations
    if ((threadIdx.x & 63) == 0) { rA[wid] = psum; rB[wid] = pcnt; rC[wid] = cfs; }
    __syncthreads();
    if (threadIdx.x == 0) {
      float ps = 0.f, pc = 0.f, cs = 0.f;
      for (int i = 0; i < 4; ++i) { ps += rA[i]; pc += rB[i]; cs += rC[i]; }
      float mean_sep = pc > 0.f ? ps / fmaxf(pc, 1.f) : 0.f;
      float ct = fmaxf(cs, 1.f);
      total += (res[b * 2 + 0] + res[b * 2 + 1] + mean_sep) / ct;
    }
  }
  if (threadIdx.x == 0) out[0] = total / (float)B;
}

extern "C" void kernel_launch(void* const* d_in, const int* in_sizes, int n_in,
                              void* d_out, int out_size, void* d_ws, size_t ws_size,
                              hipStream_t stream) {
  const float* pred = (const float*)d_in[0];
  const float* targ = (const float*)d_in[1];
  const unsigned char* nb = (const unsigned char*)d_in[2];
  const float* dw = (const float*)d_in[3];
  const int* pal = (const int*)d_in[4];
  int B = in_sizes[2];                 // 4
  int K = in_sizes[4];                 // 64 (kernels assume KINST==64)
  int HW = in_sizes[0] / (3 * B);      // 262144

  // ws layout (floats): sums[B*K*4] | res[B*2] | prep[B*K*12] | cwT_g[B*65*64]
  // then (bytes): k0c[B*HW] if it fits
  float* sums = (float*)d_ws;
  float* res = sums + (size_t)B * K * 4;
  float* prep = res + (size_t)B * 2;
  float* cwT_g = prep + (size_t)B * K * 12;
  size_t base_floats = (size_t)B * K * 4 + (size_t)B * 2 + (size_t)B * K * 12 +
                       (size_t)B * 65 * KINST;
  unsigned char* k0c = (unsigned char*)(cwT_g + (size_t)B * 65 * KINST);
  bool use_cache = ws_size >= base_floats * 4 + (size_t)B * HW;
  if (!use_cache) k0c = nullptr;

  hipMemsetAsync(d_ws, 0, ((size_t)B * K * 4 + (size_t)B * 2) * sizeof(float), stream);
  k_stats<<<dim3(256, B), 256, 0, stream>>>(pred, targ, pal, sums, k0c, HW);
  k_prep<<<B, 256, 0, stream>>>(sums, pal, nb, dw, prep, cwT_g, HW, K);
  if (use_cache)
    k_pix<true><<<dim3(512, B), 256, 0, stream>>>(pred, targ, k0c, pal, prep, cwT_g, res, HW);
  else
    k_pix<false><<<dim3(512, B), 256, 0, stream>>>(pred, targ, k0c, pal, prep, cwT_g, res, HW);
  k_final<<<1, 256, 0, stream>>>(prep, dw, res, (float*)d_out, B, K);
}

// Round 6
// 105.899 us; speedup vs baseline: 1.4216x; 1.3946x over previous
//
#include <hip/hip_runtime.h>

#define KINST 64

__device__ __forceinline__ int decode_k0(float t0, float t1, float t2,
                                         const int* pal_s) {
  int pid = (int)(fmaf(t0, 65536.f, fmaf(t1, 256.f, t2)) + 0.5f);
  if (pid >= 0 && pid < KINST && pal_s[pid] == pid) return pid;  // fast path
  for (int j = 0; j < KINST; ++j)
    if (pal_s[j] == pid) return j;
  return KINST;  // no palette match
}

// ---------------------------------------------------------------------------
// Pass 1: per-(b,k) sums + counts, k0 cache, dw-uniformity flag.
// sums: [B][K][4] = {sx,sy,sz,cnt}. LDS atomics ls[w][c][k]: bank=k%32 (2-way).
// ---------------------------------------------------------------------------
__global__ __launch_bounds__(256) void k_stats(const float* __restrict__ pred,
                                               const float* __restrict__ targ,
                                               const int* __restrict__ pal,
                                               const float* __restrict__ dw,
                                               int ndw,
                                               float* __restrict__ sums,
                                               unsigned char* __restrict__ k0c,
                                               int* __restrict__ flag_nonuni,
                                               int HW) {
  int b = blockIdx.y;
  __shared__ float ls[4][4][KINST];  // [wave][component][k]
  __shared__ int pal_s[KINST];
  for (int i = threadIdx.x; i < 4 * 4 * KINST; i += blockDim.x)
    (&ls[0][0][0])[i] = 0.f;
  for (int i = threadIdx.x; i < KINST; i += blockDim.x) pal_s[i] = pal[i];
  // distributed dw-uniformity scan
  {
    int bid = blockIdx.y * gridDim.x + blockIdx.x;
    int nblk = gridDim.x * gridDim.y;
    int per = (ndw + nblk - 1) / nblk;
    int lo = bid * per, hi = min(lo + per, ndw);
    float d0 = dw[0];
    bool nu = false;
    for (int i = lo + threadIdx.x; i < hi; i += blockDim.x) nu |= (dw[i] != d0);
    if (nu) atomicOr(flag_nonuni, 1);
  }
  __syncthreads();
  int w = threadIdx.x >> 6;
  const float* tb = targ + (size_t)b * 3 * HW;
  const float* pb = pred + (size_t)b * 3 * HW;
  unsigned char* kb = k0c ? k0c + (size_t)b * HW : nullptr;
  int nq = HW >> 2;
  const float4* tb4 = (const float4*)tb;
  const float4* pb4 = (const float4*)pb;
  for (int q = blockIdx.x * blockDim.x + threadIdx.x; q < nq;
       q += gridDim.x * blockDim.x) {
    float4 t0 = tb4[q], t1 = tb4[q + nq], t2 = tb4[q + 2 * nq];
    float4 p0 = pb4[q], p1 = pb4[q + nq], p2 = pb4[q + 2 * nq];
    int ka = decode_k0(t0.x, t1.x, t2.x, pal_s);
    int kc = decode_k0(t0.y, t1.y, t2.y, pal_s);
    int kd = decode_k0(t0.z, t1.z, t2.z, pal_s);
    int ke = decode_k0(t0.w, t1.w, t2.w, pal_s);
    if (ka < KINST) {
      atomicAdd(&ls[w][0][ka], p0.x); atomicAdd(&ls[w][1][ka], p1.x);
      atomicAdd(&ls[w][2][ka], p2.x); atomicAdd(&ls[w][3][ka], 1.f);
    }
    if (kc < KINST) {
      atomicAdd(&ls[w][0][kc], p0.y); atomicAdd(&ls[w][1][kc], p1.y);
      atomicAdd(&ls[w][2][kc], p2.y); atomicAdd(&ls[w][3][kc], 1.f);
    }
    if (kd < KINST) {
      atomicAdd(&ls[w][0][kd], p0.z); atomicAdd(&ls[w][1][kd], p1.z);
      atomicAdd(&ls[w][2][kd], p2.z); atomicAdd(&ls[w][3][kd], 1.f);
    }
    if (ke < KINST) {
      atomicAdd(&ls[w][0][ke], p0.w); atomicAdd(&ls[w][1][ke], p1.w);
      atomicAdd(&ls[w][2][ke], p2.w); atomicAdd(&ls[w][3][ke], 1.f);
    }
    if (kb) {
      uchar4 kk = make_uchar4((unsigned char)ka, (unsigned char)kc,
                              (unsigned char)kd, (unsigned char)ke);
      *(uchar4*)(kb + 4 * (size_t)q) = kk;
    }
  }
  // scalar tail (HW % 4 != 0 only)
  for (int i = (nq << 2) + blockIdx.x * blockDim.x + threadIdx.x; i < HW;
       i += gridDim.x * blockDim.x) {
    int k0 = decode_k0(tb[i], tb[i + HW], tb[i + 2 * HW], pal_s);
    if (kb) kb[i] = (unsigned char)k0;
    if (k0 < KINST) {
      atomicAdd(&ls[w][0][k0], pb[i]); atomicAdd(&ls[w][1][k0], pb[i + HW]);
      atomicAdd(&ls[w][2][k0], pb[i + 2 * HW]); atomicAdd(&ls[w][3][k0], 1.f);
    }
  }
  __syncthreads();
  for (int i = threadIdx.x; i < 4 * KINST; i += blockDim.x) {
    int c = i >> 6, k = i & 63;
    float v = ls[0][c][k] + ls[1][c][k] + ls[2][c][k] + ls[3][c][k];
    atomicAdd(&sums[((size_t)b * KINST + k) * 4 + c], v);
  }
}

// ---------------------------------------------------------------------------
// Pass 2 (hot): pixel-per-lane, 4 px/thread. k-loop broadcasts instance
// constants via uniform-address LDS reads (1 b128 + 1 b32 per k, amortized
// over 4 px). Uniform-dw fast path: no per-pair weight lookup; diagonal
// (k==k0) subtracted per pixel in epilogue. General path: cwN[k][k0] b32
// gather (bank = (k+k0)%32, ~2-way). Prep inlined per block from sums.
// res: [B][2] = {intra, inter}
// ---------------------------------------------------------------------------
template <bool USE_CACHE>
__global__ __launch_bounds__(256) void k_pix(const float* __restrict__ pred,
                                             const float* __restrict__ targ,
                                             const unsigned char* __restrict__ k0c,
                                             const int* __restrict__ pal,
                                             const unsigned char* __restrict__ nb_raw,
                                             const float* __restrict__ dw,
                                             const float* __restrict__ sums,
                                             const int* __restrict__ flag_nonuni,
                                             float* __restrict__ res, int HW) {
  int b = blockIdx.y;
  __shared__ float4 A_s[KINST + 1];      // {-2m0,-2m1,-2m2, |m|^2+1}
  __shared__ float4 Z_s[KINST + 1];      // {mz0,mz1,mz2, f_intra}
  __shared__ float W_s[KINST + 1];       // 300*dw0*scale   (uniform path)
  __shared__ float scale_s[KINST];
  __shared__ float cwN[KINST][KINST + 1];  // [k][k0] weights (general path)
  __shared__ int pal_s[KINST];
  __shared__ int nonuni_s;
  int t = threadIdx.x;
  if (t < KINST) {
    float4 s = ((const float4*)sums)[b * KINST + t];
    float cnt = s.w;
    float inv = cnt > 0.f ? 1.f / cnt : 0.f;
    float m0 = s.x * inv, m1 = s.y * inv, m2 = s.z * inv;
    bool isbg = (pal[t] == 0);
    bool nb = (nb_raw[b] != 0) || (nb_raw[4 * b] != 0);  // robust bool width
    float cf = (!isbg || !nb) ? 1.f : 0.f;
    float sc = (!isbg && cnt > 0.f) ? 10.f / (((float)HW - cnt) * sqrtf(cnt)) : 0.f;
    A_s[t] = make_float4(-2.f * m0, -2.f * m1, -2.f * m2,
                         m0 * m0 + m1 * m1 + m2 * m2 + 1.f);
    Z_s[t] = make_float4(isbg ? 0.f : m0, isbg ? 0.f : m1, isbg ? 0.f : m2,
                         cnt > 0.f ? cf / (3.f * cnt) : 0.f);
    scale_s[t] = sc;
    W_s[t] = 300.f * dw[0] * sc;
    if (!USE_CACHE) pal_s[t] = pal[t];
  }
  if (t == KINST) {
    A_s[KINST] = make_float4(0.f, 0.f, 0.f, 1.f);
    Z_s[KINST] = make_float4(0.f, 0.f, 0.f, 0.f);
    W_s[KINST] = 0.f;
  }
  if (t == 0) nonuni_s = flag_nonuni[0];
  __syncthreads();
  bool nonuni = nonuni_s != 0;
  if (nonuni) {
    for (int i = t; i < KINST * (KINST + 1); i += blockDim.x) {
      int k = i / (KINST + 1), j = i - k * (KINST + 1);
      float v = 0.f;
      if (j < KINST && j != k) v = 300.f * dw[k * KINST + j] * scale_s[k];
      cwN[k][j] = v;
    }
    __syncthreads();
  }
  const float* pb = pred + (size_t)b * 3 * HW;
  const float* tb = targ + (size_t)b * 3 * HW;
  const float4* pb4 = (const float4*)pb;
  const float4* tb4 = (const float4*)tb;
  int nq = HW >> 2;
  const uchar4* kb4 = USE_CACHE ? (const uchar4*)(k0c + (size_t)b * HW) : nullptr;
  float intra_l = 0.f, inter_l = 0.f;
  for (int q = blockIdx.x * blockDim.x + t; q < nq;
       q += gridDim.x * blockDim.x) {
    float4 P0 = pb4[q], P1 = pb4[q + nq], P2 = pb4[q + 2 * nq];
    int ka, kc, kd, ke;
    if (USE_CACHE) {
      uchar4 kk = kb4[q];
      ka = kk.x; kc = kk.y; kd = kk.z; ke = kk.w;
    } else {
      float4 T0 = tb4[q], T1 = tb4[q + nq], T2 = tb4[q + 2 * nq];
      ka = decode_k0(T0.x, T1.x, T2.x, pal_s);
      kc = decode_k0(T0.y, T1.y, T2.y, pal_s);
      kd = decode_k0(T0.z, T1.z, T2.z, pal_s);
      ke = decode_k0(T0.w, T1.w, T2.w, pal_s);
    }
    float ppa = fmaf(P0.x, P0.x, fmaf(P1.x, P1.x, P2.x * P2.x));
    float ppb = fmaf(P0.y, P0.y, fmaf(P1.y, P1.y, P2.y * P2.y));
    float ppc = fmaf(P0.z, P0.z, fmaf(P1.z, P1.z, P2.z * P2.z));
    float ppd = fmaf(P0.w, P0.w, fmaf(P1.w, P1.w, P2.w * P2.w));
    float aa = 0.f, ab = 0.f, ac = 0.f, ad = 0.f;
    if (!nonuni) {
      #pragma unroll 8
      for (int k = 0; k < KINST; ++k) {
        float4 a = A_s[k];          // uniform addr -> broadcast b128
        float wv = W_s[k];          // uniform addr -> broadcast b32
        float ra = __builtin_amdgcn_rcpf(
            ppa + fmaf(P0.x, a.x, fmaf(P1.x, a.y, fmaf(P2.x, a.z, a.w))));
        float rb = __builtin_amdgcn_rcpf(
            ppb + fmaf(P0.y, a.x, fmaf(P1.y, a.y, fmaf(P2.y, a.z, a.w))));
        float rc = __builtin_amdgcn_rcpf(
            ppc + fmaf(P0.z, a.x, fmaf(P1.z, a.y, fmaf(P2.z, a.z, a.w))));
        float rd = __builtin_amdgcn_rcpf(
            ppd + fmaf(P0.w, a.x, fmaf(P1.w, a.y, fmaf(P2.w, a.z, a.w))));
        aa = fmaf(ra, wv, aa); ab = fmaf(rb, wv, ab);
        ac = fmaf(rc, wv, ac); ad = fmaf(rd, wv, ad);
      }
      // diagonal (k==k0) subtract + invalid-pixel mask, per px
      {
        float4 a = A_s[ka]; float wv = W_s[ka];
        float r = __builtin_amdgcn_rcpf(
            ppa + fmaf(P0.x, a.x, fmaf(P1.x, a.y, fmaf(P2.x, a.z, a.w))));
        aa = (ka < KINST) ? aa - wv * r : 0.f;
      }
      {
        float4 a = A_s[kc]; float wv = W_s[kc];
        float r = __builtin_amdgcn_rcpf(
            ppb + fmaf(P0.y, a.x, fmaf(P1.y, a.y, fmaf(P2.y, a.z, a.w))));
        ab = (kc < KINST) ? ab - wv * r : 0.f;
      }
      {
        float4 a = A_s[kd]; float wv = W_s[kd];
        float r = __builtin_amdgcn_rcpf(
            ppc + fmaf(P0.z, a.x, fmaf(P1.z, a.y, fmaf(P2.z, a.z, a.w))));
        ac = (kd < KINST) ? ac - wv * r : 0.f;
      }
      {
        float4 a = A_s[ke]; float wv = W_s[ke];
        float r = __builtin_amdgcn_rcpf(
            ppd + fmaf(P0.w, a.x, fmaf(P1.w, a.y, fmaf(P2.w, a.z, a.w))));
        ad = (ke < KINST) ? ad - wv * r : 0.f;
      }
    } else {
      #pragma unroll 4
      for (int k = 0; k < KINST; ++k) {
        float4 a = A_s[k];  // uniform broadcast
        float ra = __builtin_amdgcn_rcpf(
            ppa + fmaf(P0.x, a.x, fmaf(P1.x, a.y, fmaf(P2.x, a.z, a.w))));
        float rb = __builtin_amdgcn_rcpf(
            ppb + fmaf(P0.y, a.x, fmaf(P1.y, a.y, fmaf(P2.y, a.z, a.w))));
        float rc = __builtin_amdgcn_rcpf(
            ppc + fmaf(P0.z, a.x, fmaf(P1.z, a.y, fmaf(P2.z, a.z, a.w))));
        float rd = __builtin_amdgcn_rcpf(
            ppd + fmaf(P0.w, a.x, fmaf(P1.w, a.y, fmaf(P2.w, a.z, a.w))));
        // cwN handles diag (=0), invalid k0=64 (=0), scale & dw fold
        aa = fmaf(ra, cwN[k][ka], aa); ab = fmaf(rb, cwN[k][kc], ab);
        ac = fmaf(rc, cwN[k][kd], ac); ad = fmaf(rd, cwN[k][ke], ad);
      }
    }
    inter_l += (aa + ab) + (ac + ad);
    // intra: huber toward own bg-zeroed mean; f_intra folds cf/(3*cnt)
    {
      float4 z = Z_s[ka];
      float q0 = fabsf(P0.x - z.x), q1 = fabsf(P1.x - z.y), q2 = fabsf(P2.x - z.z);
      float hp = (q0 < 1.f ? 0.5f * q0 * q0 : q0 - 0.5f) +
                 (q1 < 1.f ? 0.5f * q1 * q1 : q1 - 0.5f) +
                 (q2 < 1.f ? 0.5f * q2 * q2 : q2 - 0.5f);
      intra_l = fmaf(hp, z.w, intra_l);
    }
    {
      float4 z = Z_s[kc];
      float q0 = fabsf(P0.y - z.x), q1 = fabsf(P1.y - z.y), q2 = fabsf(P2.y - z.z);
      float hp = (q0 < 1.f ? 0.5f * q0 * q0 : q0 - 0.5f) +
                 (q1 < 1.f ? 0.5f * q1 * q1 : q1 - 0.5f) +
                 (q2 < 1.f ? 0.5f * q2 * q2 : q2 - 0.5f);
      intra_l = fmaf(hp, z.w, intra_l);
    }
    {
      float4 z = Z_s[kd];
      float q0 = fabsf(P0.z - z.x), q1 = fabsf(P1.z - z.y), q2 = fabsf(P2.z - z.z);
      float hp = (q0 < 1.f ? 0.5f * q0 * q0 : q0 - 0.5f) +
                 (q1 < 1.f ? 0.5f * q1 * q1 : q1 - 0.5f) +
                 (q2 < 1.f ? 0.5f * q2 * q2 : q2 - 0.5f);
      intra_l = fmaf(hp, z.w, intra_l);
    }
    {
      float4 z = Z_s[ke];
      float q0 = fabsf(P0.w - z.x), q1 = fabsf(P1.w - z.y), q2 = fabsf(P2.w - z.z);
      float hp = (q0 < 1.f ? 0.5f * q0 * q0 : q0 - 0.5f) +
                 (q1 < 1.f ? 0.5f * q1 * q1 : q1 - 0.5f) +
                 (q2 < 1.f ? 0.5f * q2 * q2 : q2 - 0.5f);
      intra_l = fmaf(hp, z.w, intra_l);
    }
  }
  // scalar tail pixels (HW % 4 != 0 only)
  for (int i = (nq << 2) + blockIdx.x * blockDim.x + t; i < HW;
       i += gridDim.x * blockDim.x) {
    float p0 = pb[i], p1 = pb[i + HW], p2 = pb[i + 2 * HW];
    int k0 = USE_CACHE ? (int)k0c[(size_t)b * HW + i]
                       : decode_k0(tb[i], tb[i + HW], tb[i + 2 * HW], pal_s);
    float pp = fmaf(p0, p0, fmaf(p1, p1, p2 * p2));
    float acc = 0.f;
    for (int k = 0; k < KINST; ++k) {
      float4 a = A_s[k];
      float r = __builtin_amdgcn_rcpf(
          pp + fmaf(p0, a.x, fmaf(p1, a.y, fmaf(p2, a.z, a.w))));
      float c = nonuni ? cwN[k][k0] : ((k == k0 || k0 >= KINST) ? 0.f : W_s[k]);
      acc = fmaf(r, c, acc);
    }
    inter_l += acc;
    float4 z = Z_s[k0];
    float q0 = fabsf(p0 - z.x), q1 = fabsf(p1 - z.y), q2 = fabsf(p2 - z.z);
    float hp = (q0 < 1.f ? 0.5f * q0 * q0 : q0 - 0.5f) +
               (q1 < 1.f ? 0.5f * q1 * q1 : q1 - 0.5f) +
               (q2 < 1.f ? 0.5f * q2 * q2 : q2 - 0.5f);
    intra_l = fmaf(hp, z.w, intra_l);
  }
  for (int o = 32; o > 0; o >>= 1) {
    intra_l += __shfl_down(intra_l, o, 64);
    inter_l += __shfl_down(inter_l, o, 64);
  }
  __shared__ float rA[4], rB[4];
  int wid = threadIdx.x >> 6;
  if ((threadIdx.x & 63) == 0) { rA[wid] = intra_l; rB[wid] = inter_l; }
  __syncthreads();
  if (threadIdx.x == 0) {
    float a = 0.f, c = 0.f;
    for (int i = 0; i < 4; ++i) { a += rA[i]; c += rB[i]; }
    atomicAdd(&res[b * 2 + 0], a);
    atomicAdd(&res[b * 2 + 1], c);
  }
}

// ---------------------------------------------------------------------------
// Pass 3: single block; recompute means from sums, pairwise repulsion, combine.
// ---------------------------------------------------------------------------
__global__ __launch_bounds__(256) void k_final(const float* __restrict__ sums,
                                               const int* __restrict__ pal,
                                               const unsigned char* __restrict__ nb_raw,
                                               const float* __restrict__ dw,
                                               const float* __restrict__ res,
                                               float* __restrict__ out,
                                               int B, int HW) {
  __shared__ float4 zf[KINST];  // {mz0,mz1,mz2, cf}
  __shared__ float rA[4], rB[4], rC[4];
  float total = 0.f;
  for (int b = 0; b < B; ++b) {
    __syncthreads();
    if (threadIdx.x < KINST) {
      int k = threadIdx.x;
      float4 s = ((const float4*)sums)[b * KINST + k];
      float cnt = s.w;
      float inv = cnt > 0.f ? 1.f / cnt : 0.f;
      bool isbg = (pal[k] == 0);
      bool nb = (nb_raw[b] != 0) || (nb_raw[4 * b] != 0);
      float cf = (!isbg || !nb) ? 1.f : 0.f;
      zf[k] = make_float4(isbg ? 0.f : s.x * inv, isbg ? 0.f : s.y * inv,
                          isbg ? 0.f : s.z * inv, cf);
    }
    __syncthreads();
    float psum = 0.f, pcnt = 0.f, cfs = 0.f;
    for (int idx = threadIdx.x; idx < KINST * KINST; idx += blockDim.x) {
      int j = idx >> 6, k = idx & 63;
      if (j < k) {
        float4 a = zf[j], c4 = zf[k];
        float m = a.w * c4.w;
        float d0 = a.x - c4.x, d1 = a.y - c4.y, d2 = a.z - c4.z;
        float sqd = d0 * d0 + d1 * d1 + d2 * d2;
        psum += dw[j * KINST + k] * 300.f / (sqd + 1.f) * m;
        pcnt += m;
      }
    }
    if (threadIdx.x < KINST) cfs = zf[threadIdx.x].w;
    for (int o = 32; o > 0; o >>= 1) {
      psum += __shfl_down(psum, o, 64);
      pcnt += __shfl_down(pcnt, o, 64);
      cfs += __shfl_down(cfs, o, 64);
    }
    int wid = threadIdx.x >> 6;
    if ((threadIdx.x & 63) == 0) { rA[wid] = psum; rB[wid] = pcnt; rC[wid] = cfs; }
    __syncthreads();
    if (threadIdx.x == 0) {
      float ps = 0.f, pc = 0.f, cs = 0.f;
      for (int i = 0; i < 4; ++i) { ps += rA[i]; pc += rB[i]; cs += rC[i]; }
      float mean_sep = pc > 0.f ? ps / fmaxf(pc, 1.f) : 0.f;
      float ct = fmaxf(cs, 1.f);
      total += (res[b * 2 + 0] + res[b * 2 + 1] + mean_sep) / ct;
    }
  }
  if (threadIdx.x == 0) out[0] = total / (float)B;
}

extern "C" void kernel_launch(void* const* d_in, const int* in_sizes, int n_in,
                              void* d_out, int out_size, void* d_ws, size_t ws_size,
                              hipStream_t stream) {
  const float* pred = (const float*)d_in[0];
  const float* targ = (const float*)d_in[1];
  const unsigned char* nb = (const unsigned char*)d_in[2];
  const float* dw = (const float*)d_in[3];
  const int* pal = (const int*)d_in[4];
  int B = in_sizes[2];                 // 4
  int ndw = in_sizes[3];               // K*K = 4096
  int HW = in_sizes[0] / (3 * B);      // 262144  (kernels assume K==64)

  // ws layout (floats): sums[B*64*4 = 1024] | res[8] | flag[1] | pad -> 1040
  // then bytes: k0c[B*HW] if it fits
  float* sums = (float*)d_ws;
  float* res = sums + 1024;
  int* flag_nonuni = (int*)(sums + 1032);
  unsigned char* k0c = (unsigned char*)(sums + 1040);
  bool use_cache = ws_size >= 1040 * 4 + (size_t)B * HW;
  if (!use_cache) k0c = nullptr;

  hipMemsetAsync(d_ws, 0, 1040 * sizeof(float), stream);
  k_stats<<<dim3(256, B), 256, 0, stream>>>(pred, targ, pal, dw, ndw, sums, k0c,
                                            flag_nonuni, HW);
  int gx = max(1, min(256, (HW / 4 + 255) / 256));
  if (use_cache)
    k_pix<true><<<dim3(gx, B), 256, 0, stream>>>(pred, targ, k0c, pal, nb, dw,
                                                 sums, flag_nonuni, res, HW);
  else
    k_pix<false><<<dim3(gx, B), 256, 0, stream>>>(pred, targ, k0c, pal, nb, dw,
                                                  sums, flag_nonuni, res, HW);
  k_final<<<1, 256, 0, stream>>>(sums, pal, nb, dw, res, (float*)d_out, B, HW);
}

// Round 7
// 65.120 us; speedup vs baseline: 2.3118x; 1.6262x over previous
//
#include <hip/hip_runtime.h>

#define KINST 64

__device__ __forceinline__ int decode_k0(float t0, float t1, float t2,
                                         const int* pal_s) {
  int pid = (int)(fmaf(t0, 65536.f, fmaf(t1, 256.f, t2)) + 0.5f);
  if (pid >= 0 && pid < KINST && pal_s[pid] == pid) return pid;  // fast path
  for (int j = 0; j < KINST; ++j)
    if (pal_s[j] == pid) return j;
  return KINST;  // no palette match
}

// ---------------------------------------------------------------------------
// Pass 1: per-(b,block) PARTIAL histograms via LDS atomics; finalize with
// PLAIN coalesced stores (no global atomics — they were the 52us bottleneck).
// partialS layout: [B][nbs][256] where 256 = c*64+k (c=component, k=instance)
// ---------------------------------------------------------------------------
__global__ __launch_bounds__(256) void k_stats(const float* __restrict__ pred,
                                               const float* __restrict__ targ,
                                               const int* __restrict__ pal,
                                               float* __restrict__ partialS,
                                               unsigned char* __restrict__ k0c,
                                               int HW) {
  int b = blockIdx.y;
  __shared__ float ls[4][4][KINST];  // [wave][component][k]
  __shared__ int pal_s[KINST];
  for (int i = threadIdx.x; i < 4 * 4 * KINST; i += blockDim.x)
    (&ls[0][0][0])[i] = 0.f;
  for (int i = threadIdx.x; i < KINST; i += blockDim.x) pal_s[i] = pal[i];
  __syncthreads();
  int w = threadIdx.x >> 6;
  const float* tb = targ + (size_t)b * 3 * HW;
  const float* pb = pred + (size_t)b * 3 * HW;
  unsigned char* kb = k0c ? k0c + (size_t)b * HW : nullptr;
  int nq = HW >> 2;
  const float4* tb4 = (const float4*)tb;
  const float4* pb4 = (const float4*)pb;
  for (int q = blockIdx.x * blockDim.x + threadIdx.x; q < nq;
       q += gridDim.x * blockDim.x) {
    float4 t0 = tb4[q], t1 = tb4[q + nq], t2 = tb4[q + 2 * nq];
    float4 p0 = pb4[q], p1 = pb4[q + nq], p2 = pb4[q + 2 * nq];
    int ka = decode_k0(t0.x, t1.x, t2.x, pal_s);
    int kc = decode_k0(t0.y, t1.y, t2.y, pal_s);
    int kd = decode_k0(t0.z, t1.z, t2.z, pal_s);
    int ke = decode_k0(t0.w, t1.w, t2.w, pal_s);
    if (ka < KINST) {
      atomicAdd(&ls[w][0][ka], p0.x); atomicAdd(&ls[w][1][ka], p1.x);
      atomicAdd(&ls[w][2][ka], p2.x); atomicAdd(&ls[w][3][ka], 1.f);
    }
    if (kc < KINST) {
      atomicAdd(&ls[w][0][kc], p0.y); atomicAdd(&ls[w][1][kc], p1.y);
      atomicAdd(&ls[w][2][kc], p2.y); atomicAdd(&ls[w][3][kc], 1.f);
    }
    if (kd < KINST) {
      atomicAdd(&ls[w][0][kd], p0.z); atomicAdd(&ls[w][1][kd], p1.z);
      atomicAdd(&ls[w][2][kd], p2.z); atomicAdd(&ls[w][3][kd], 1.f);
    }
    if (ke < KINST) {
      atomicAdd(&ls[w][0][ke], p0.w); atomicAdd(&ls[w][1][ke], p1.w);
      atomicAdd(&ls[w][2][ke], p2.w); atomicAdd(&ls[w][3][ke], 1.f);
    }
    if (kb) {
      uchar4 kk = make_uchar4((unsigned char)ka, (unsigned char)kc,
                              (unsigned char)kd, (unsigned char)ke);
      *(uchar4*)(kb + 4 * (size_t)q) = kk;
    }
  }
  // scalar tail (HW % 4 != 0 only)
  for (int i = (nq << 2) + blockIdx.x * blockDim.x + threadIdx.x; i < HW;
       i += gridDim.x * blockDim.x) {
    int k0 = decode_k0(tb[i], tb[i + HW], tb[i + 2 * HW], pal_s);
    if (kb) kb[i] = (unsigned char)k0;
    if (k0 < KINST) {
      atomicAdd(&ls[w][0][k0], pb[i]); atomicAdd(&ls[w][1][k0], pb[i + HW]);
      atomicAdd(&ls[w][2][k0], pb[i + 2 * HW]); atomicAdd(&ls[w][3][k0], 1.f);
    }
  }
  __syncthreads();
  // plain coalesced store of this block's partial histogram
  float* out = partialS + ((size_t)b * gridDim.x + blockIdx.x) * 256;
  int i = threadIdx.x;  // i = c*64+k
  int c = i >> 6, k = i & 63;
  out[i] = ls[0][c][k] + ls[1][c][k] + ls[2][c][k] + ls[3][c][k];
}

// ---------------------------------------------------------------------------
// Pass 2 (tiny, grid=B): reduce partials -> sums[B][K][4]; dw-uniformity flag.
// ---------------------------------------------------------------------------
__global__ __launch_bounds__(256) void k_reduce(const float* __restrict__ partialS,
                                                const float* __restrict__ dw,
                                                int ndw, int nbs,
                                                float* __restrict__ sums,
                                                int* __restrict__ flagp, int B) {
  int b = blockIdx.x;
  int i = threadIdx.x;
  const float* src = partialS + (size_t)b * nbs * 256;
  float a0 = 0.f, a1 = 0.f, a2 = 0.f, a3 = 0.f;
  int bx = 0;
  #pragma unroll 4
  for (; bx + 4 <= nbs; bx += 4) {
    a0 += src[(size_t)(bx + 0) * 256 + i];
    a1 += src[(size_t)(bx + 1) * 256 + i];
    a2 += src[(size_t)(bx + 2) * 256 + i];
    a3 += src[(size_t)(bx + 3) * 256 + i];
  }
  for (; bx < nbs; ++bx) a0 += src[(size_t)bx * 256 + i];
  float acc = (a0 + a1) + (a2 + a3);
  int c = i >> 6, k = i & 63;
  sums[((size_t)b * KINST + k) * 4 + c] = acc;
  // dw-uniformity scan (chunked across the B blocks)
  __shared__ int nu_sh;
  if (i == 0) nu_sh = 0;
  __syncthreads();
  int per = (ndw + B - 1) / B;
  int lo = b * per, hi = min(lo + per, ndw);
  float d0 = dw[0];
  int nu = 0;
  for (int x = lo + i; x < hi; x += blockDim.x) nu |= (dw[x] != d0);
  if (nu) atomicOr(&nu_sh, 1);
  __syncthreads();
  if (i == 0) flagp[b] = nu_sh;
}

// ---------------------------------------------------------------------------
// Pass 3 (hot): pixel-per-lane, 4 px/thread; uniform-address LDS broadcasts
// per k; uniform-dw fast path (diag subtracted in epilogue); general path
// via cwN gather. Per-block result written with PLAIN stores to res_part.
// res_part: [B][gridDim.x][2] = {intra, inter}
// ---------------------------------------------------------------------------
template <bool USE_CACHE>
__global__ __launch_bounds__(256) void k_pix(const float* __restrict__ pred,
                                             const float* __restrict__ targ,
                                             const unsigned char* __restrict__ k0c,
                                             const int* __restrict__ pal,
                                             const unsigned char* __restrict__ nb_raw,
                                             const float* __restrict__ dw,
                                             const float* __restrict__ sums,
                                             const int* __restrict__ flagp,
                                             float* __restrict__ res_part,
                                             int HW, int B) {
  int b = blockIdx.y;
  __shared__ float4 A_s[KINST + 1];      // {-2m0,-2m1,-2m2, |m|^2+1}
  __shared__ float4 Z_s[KINST + 1];      // {mz0,mz1,mz2, f_intra}
  __shared__ float W_s[KINST + 1];       // 300*dw0*scale   (uniform path)
  __shared__ float scale_s[KINST];
  __shared__ float cwN[KINST][KINST + 1];  // [k][k0] weights (general path)
  __shared__ int pal_s[KINST];
  __shared__ int nonuni_s;
  int t = threadIdx.x;
  if (t < KINST) {
    float4 s = ((const float4*)sums)[b * KINST + t];
    float cnt = s.w;
    float inv = cnt > 0.f ? 1.f / cnt : 0.f;
    float m0 = s.x * inv, m1 = s.y * inv, m2 = s.z * inv;
    bool isbg = (pal[t] == 0);
    bool nb = (nb_raw[b] != 0) || (nb_raw[4 * b] != 0);  // robust bool width
    float cf = (!isbg || !nb) ? 1.f : 0.f;
    float sc = (!isbg && cnt > 0.f) ? 10.f / (((float)HW - cnt) * sqrtf(cnt)) : 0.f;
    A_s[t] = make_float4(-2.f * m0, -2.f * m1, -2.f * m2,
                         m0 * m0 + m1 * m1 + m2 * m2 + 1.f);
    Z_s[t] = make_float4(isbg ? 0.f : m0, isbg ? 0.f : m1, isbg ? 0.f : m2,
                         cnt > 0.f ? cf / (3.f * cnt) : 0.f);
    scale_s[t] = sc;
    W_s[t] = 300.f * dw[0] * sc;
    if (!USE_CACHE) pal_s[t] = pal[t];
  }
  if (t == KINST) {
    A_s[KINST] = make_float4(0.f, 0.f, 0.f, 1.f);
    Z_s[KINST] = make_float4(0.f, 0.f, 0.f, 0.f);
    W_s[KINST] = 0.f;
  }
  if (t == 0) {
    int f = 0;
    for (int bb = 0; bb < B; ++bb) f |= flagp[bb];
    nonuni_s = f;
  }
  __syncthreads();
  bool nonuni = nonuni_s != 0;
  if (nonuni) {
    for (int i = t; i < KINST * (KINST + 1); i += blockDim.x) {
      int k = i / (KINST + 1), j = i - k * (KINST + 1);
      float v = 0.f;
      if (j < KINST && j != k) v = 300.f * dw[k * KINST + j] * scale_s[k];
      cwN[k][j] = v;
    }
    __syncthreads();
  }
  const float* pb = pred + (size_t)b * 3 * HW;
  const float* tb = targ + (size_t)b * 3 * HW;
  const float4* pb4 = (const float4*)pb;
  const float4* tb4 = (const float4*)tb;
  int nq = HW >> 2;
  const uchar4* kb4 = USE_CACHE ? (const uchar4*)(k0c + (size_t)b * HW) : nullptr;
  float intra_l = 0.f, inter_l = 0.f;
  for (int q = blockIdx.x * blockDim.x + t; q < nq;
       q += gridDim.x * blockDim.x) {
    float4 P0 = pb4[q], P1 = pb4[q + nq], P2 = pb4[q + 2 * nq];
    int ka, kc, kd, ke;
    if (USE_CACHE) {
      uchar4 kk = kb4[q];
      ka = kk.x; kc = kk.y; kd = kk.z; ke = kk.w;
    } else {
      float4 T0 = tb4[q], T1 = tb4[q + nq], T2 = tb4[q + 2 * nq];
      ka = decode_k0(T0.x, T1.x, T2.x, pal_s);
      kc = decode_k0(T0.y, T1.y, T2.y, pal_s);
      kd = decode_k0(T0.z, T1.z, T2.z, pal_s);
      ke = decode_k0(T0.w, T1.w, T2.w, pal_s);
    }
    float ppa = fmaf(P0.x, P0.x, fmaf(P1.x, P1.x, P2.x * P2.x));
    float ppb = fmaf(P0.y, P0.y, fmaf(P1.y, P1.y, P2.y * P2.y));
    float ppc = fmaf(P0.z, P0.z, fmaf(P1.z, P1.z, P2.z * P2.z));
    float ppd = fmaf(P0.w, P0.w, fmaf(P1.w, P1.w, P2.w * P2.w));
    float aa = 0.f, ab = 0.f, ac = 0.f, ad = 0.f;
    if (!nonuni) {
      #pragma unroll 8
      for (int k = 0; k < KINST; ++k) {
        float4 a = A_s[k];          // uniform addr -> broadcast b128
        float wv = W_s[k];          // uniform addr -> broadcast b32
        float ra = __builtin_amdgcn_rcpf(
            ppa + fmaf(P0.x, a.x, fmaf(P1.x, a.y, fmaf(P2.x, a.z, a.w))));
        float rb = __builtin_amdgcn_rcpf(
            ppb + fmaf(P0.y, a.x, fmaf(P1.y, a.y, fmaf(P2.y, a.z, a.w))));
        float rc = __builtin_amdgcn_rcpf(
            ppc + fmaf(P0.z, a.x, fmaf(P1.z, a.y, fmaf(P2.z, a.z, a.w))));
        float rd = __builtin_amdgcn_rcpf(
            ppd + fmaf(P0.w, a.x, fmaf(P1.w, a.y, fmaf(P2.w, a.z, a.w))));
        aa = fmaf(ra, wv, aa); ab = fmaf(rb, wv, ab);
        ac = fmaf(rc, wv, ac); ad = fmaf(rd, wv, ad);
      }
      // diagonal (k==k0) subtract + invalid-pixel mask, per px
      {
        float4 a = A_s[ka]; float wv = W_s[ka];
        float r = __builtin_amdgcn_rcpf(
            ppa + fmaf(P0.x, a.x, fmaf(P1.x, a.y, fmaf(P2.x, a.z, a.w))));
        aa = (ka < KINST) ? aa - wv * r : 0.f;
      }
      {
        float4 a = A_s[kc]; float wv = W_s[kc];
        float r = __builtin_amdgcn_rcpf(
            ppb + fmaf(P0.y, a.x, fmaf(P1.y, a.y, fmaf(P2.y, a.z, a.w))));
        ab = (kc < KINST) ? ab - wv * r : 0.f;
      }
      {
        float4 a = A_s[kd]; float wv = W_s[kd];
        float r = __builtin_amdgcn_rcpf(
            ppc + fmaf(P0.z, a.x, fmaf(P1.z, a.y, fmaf(P2.z, a.z, a.w))));
        ac = (kd < KINST) ? ac - wv * r : 0.f;
      }
      {
        float4 a = A_s[ke]; float wv = W_s[ke];
        float r = __builtin_amdgcn_rcpf(
            ppd + fmaf(P0.w, a.x, fmaf(P1.w, a.y, fmaf(P2.w, a.z, a.w))));
        ad = (ke < KINST) ? ad - wv * r : 0.f;
      }
    } else {
      #pragma unroll 4
      for (int k = 0; k < KINST; ++k) {
        float4 a = A_s[k];  // uniform broadcast
        float ra = __builtin_amdgcn_rcpf(
            ppa + fmaf(P0.x, a.x, fmaf(P1.x, a.y, fmaf(P2.x, a.z, a.w))));
        float rb = __builtin_amdgcn_rcpf(
            ppb + fmaf(P0.y, a.x, fmaf(P1.y, a.y, fmaf(P2.y, a.z, a.w))));
        float rc = __builtin_amdgcn_rcpf(
            ppc + fmaf(P0.z, a.x, fmaf(P1.z, a.y, fmaf(P2.z, a.z, a.w))));
        float rd = __builtin_amdgcn_rcpf(
            ppd + fmaf(P0.w, a.x, fmaf(P1.w, a.y, fmaf(P2.w, a.z, a.w))));
        // cwN handles diag (=0), invalid k0=64 (=0), scale & dw fold
        aa = fmaf(ra, cwN[k][ka], aa); ab = fmaf(rb, cwN[k][kc], ab);
        ac = fmaf(rc, cwN[k][kd], ac); ad = fmaf(rd, cwN[k][ke], ad);
      }
    }
    inter_l += (aa + ab) + (ac + ad);
    // intra: huber toward own bg-zeroed mean; f_intra folds cf/(3*cnt)
    {
      float4 z = Z_s[ka];
      float q0 = fabsf(P0.x - z.x), q1 = fabsf(P1.x - z.y), q2 = fabsf(P2.x - z.z);
      float hp = (q0 < 1.f ? 0.5f * q0 * q0 : q0 - 0.5f) +
                 (q1 < 1.f ? 0.5f * q1 * q1 : q1 - 0.5f) +
                 (q2 < 1.f ? 0.5f * q2 * q2 : q2 - 0.5f);
      intra_l = fmaf(hp, z.w, intra_l);
    }
    {
      float4 z = Z_s[kc];
      float q0 = fabsf(P0.y - z.x), q1 = fabsf(P1.y - z.y), q2 = fabsf(P2.y - z.z);
      float hp = (q0 < 1.f ? 0.5f * q0 * q0 : q0 - 0.5f) +
                 (q1 < 1.f ? 0.5f * q1 * q1 : q1 - 0.5f) +
                 (q2 < 1.f ? 0.5f * q2 * q2 : q2 - 0.5f);
      intra_l = fmaf(hp, z.w, intra_l);
    }
    {
      float4 z = Z_s[kd];
      float q0 = fabsf(P0.z - z.x), q1 = fabsf(P1.z - z.y), q2 = fabsf(P2.z - z.z);
      float hp = (q0 < 1.f ? 0.5f * q0 * q0 : q0 - 0.5f) +
                 (q1 < 1.f ? 0.5f * q1 * q1 : q1 - 0.5f) +
                 (q2 < 1.f ? 0.5f * q2 * q2 : q2 - 0.5f);
      intra_l = fmaf(hp, z.w, intra_l);
    }
    {
      float4 z = Z_s[ke];
      float q0 = fabsf(P0.w - z.x), q1 = fabsf(P1.w - z.y), q2 = fabsf(P2.w - z.z);
      float hp = (q0 < 1.f ? 0.5f * q0 * q0 : q0 - 0.5f) +
                 (q1 < 1.f ? 0.5f * q1 * q1 : q1 - 0.5f) +
                 (q2 < 1.f ? 0.5f * q2 * q2 : q2 - 0.5f);
      intra_l = fmaf(hp, z.w, intra_l);
    }
  }
  // scalar tail pixels (HW % 4 != 0 only)
  for (int i = (nq << 2) + blockIdx.x * blockDim.x + t; i < HW;
       i += gridDim.x * blockDim.x) {
    float p0 = pb[i], p1 = pb[i + HW], p2 = pb[i + 2 * HW];
    int k0 = USE_CACHE ? (int)k0c[(size_t)b * HW + i]
                       : decode_k0(tb[i], tb[i + HW], tb[i + 2 * HW], pal_s);
    float pp = fmaf(p0, p0, fmaf(p1, p1, p2 * p2));
    float acc = 0.f;
    for (int k = 0; k < KINST; ++k) {
      float4 a = A_s[k];
      float r = __builtin_amdgcn_rcpf(
          pp + fmaf(p0, a.x, fmaf(p1, a.y, fmaf(p2, a.z, a.w))));
      float c = nonuni ? cwN[k][k0] : ((k == k0 || k0 >= KINST) ? 0.f : W_s[k]);
      acc = fmaf(r, c, acc);
    }
    inter_l += acc;
    float4 z = Z_s[k0];
    float q0 = fabsf(p0 - z.x), q1 = fabsf(p1 - z.y), q2 = fabsf(p2 - z.z);
    float hp = (q0 < 1.f ? 0.5f * q0 * q0 : q0 - 0.5f) +
               (q1 < 1.f ? 0.5f * q1 * q1 : q1 - 0.5f) +
               (q2 < 1.f ? 0.5f * q2 * q2 : q2 - 0.5f);
    intra_l = fmaf(hp, z.w, intra_l);
  }
  for (int o = 32; o > 0; o >>= 1) {
    intra_l += __shfl_down(intra_l, o, 64);
    inter_l += __shfl_down(inter_l, o, 64);
  }
  __shared__ float rA[4], rB[4];
  int wid = threadIdx.x >> 6;
  if ((threadIdx.x & 63) == 0) { rA[wid] = intra_l; rB[wid] = inter_l; }
  __syncthreads();
  if (threadIdx.x == 0) {
    float a = 0.f, c = 0.f;
    for (int i = 0; i < 4; ++i) { a += rA[i]; c += rB[i]; }
    float* rp = res_part + ((size_t)b * gridDim.x + blockIdx.x) * 2;
    rp[0] = a; rp[1] = c;  // plain store, no atomics
  }
}

// ---------------------------------------------------------------------------
// Pass 4: single block; reduce res_part (fixed order), recompute means from
// sums, pairwise repulsion, final combine -> out[0].
// ---------------------------------------------------------------------------
__global__ __launch_bounds__(256) void k_final(const float* __restrict__ sums,
                                               const int* __restrict__ pal,
                                               const unsigned char* __restrict__ nb_raw,
                                               const float* __restrict__ dw,
                                               const float* __restrict__ res_part,
                                               int ngx,
                                               float* __restrict__ out,
                                               int B, int HW) {
  __shared__ float4 zf[KINST];  // {mz0,mz1,mz2, cf}
  __shared__ float rA[4], rB[4], rC[4], rD[4], rE[4];
  float total = 0.f;
  for (int b = 0; b < B; ++b) {
    __syncthreads();
    if (threadIdx.x < KINST) {
      int k = threadIdx.x;
      float4 s = ((const float4*)sums)[b * KINST + k];
      float cnt = s.w;
      float inv = cnt > 0.f ? 1.f / cnt : 0.f;
      bool isbg = (pal[k] == 0);
      bool nb = (nb_raw[b] != 0) || (nb_raw[4 * b] != 0);
      float cf = (!isbg || !nb) ? 1.f : 0.f;
      zf[k] = make_float4(isbg ? 0.f : s.x * inv, isbg ? 0.f : s.y * inv,
                          isbg ? 0.f : s.z * inv, cf);
    }
    __syncthreads();
    float psum = 0.f, pcnt = 0.f, cfs = 0.f, ra = 0.f, rc = 0.f;
    for (int idx = threadIdx.x; idx < KINST * KINST; idx += blockDim.x) {
      int j = idx >> 6, k = idx & 63;
      if (j < k) {
        float4 a = zf[j], c4 = zf[k];
        float m = a.w * c4.w;
        float d0 = a.x - c4.x, d1 = a.y - c4.y, d2 = a.z - c4.z;
        float sqd = d0 * d0 + d1 * d1 + d2 * d2;
        psum += dw[j * KINST + k] * 300.f / (sqd + 1.f) * m;
        pcnt += m;
      }
    }
    if (threadIdx.x < KINST) cfs = zf[threadIdx.x].w;
    for (int bx = threadIdx.x; bx < ngx; bx += blockDim.x) {
      const float* rp = res_part + ((size_t)b * ngx + bx) * 2;
      ra += rp[0]; rc += rp[1];
    }
    for (int o = 32; o > 0; o >>= 1) {
      psum += __shfl_down(psum, o, 64);
      pcnt += __shfl_down(pcnt, o, 64);
      cfs += __shfl_down(cfs, o, 64);
      ra += __shfl_down(ra, o, 64);
      rc += __shfl_down(rc, o, 64);
    }
    int wid = threadIdx.x >> 6;
    if ((threadIdx.x & 63) == 0) {
      rA[wid] = psum; rB[wid] = pcnt; rC[wid] = cfs; rD[wid] = ra; rE[wid] = rc;
    }
    __syncthreads();
    if (threadIdx.x == 0) {
      float ps = 0.f, pc = 0.f, cs = 0.f, sa = 0.f, sc2 = 0.f;
      for (int i = 0; i < 4; ++i) {
        ps += rA[i]; pc += rB[i]; cs += rC[i]; sa += rD[i]; sc2 += rE[i];
      }
      float mean_sep = pc > 0.f ? ps / fmaxf(pc, 1.f) : 0.f;
      float ct = fmaxf(cs, 1.f);
      total += (sa + sc2 + mean_sep) / ct;
    }
  }
  if (threadIdx.x == 0) out[0] = total / (float)B;
}

extern "C" void kernel_launch(void* const* d_in, const int* in_sizes, int n_in,
                              void* d_out, int out_size, void* d_ws, size_t ws_size,
                              hipStream_t stream) {
  const float* pred = (const float*)d_in[0];
  const float* targ = (const float*)d_in[1];
  const unsigned char* nb = (const unsigned char*)d_in[2];
  const float* dw = (const float*)d_in[3];
  const int* pal = (const int*)d_in[4];
  int B = in_sizes[2];                 // 4
  int ndw = in_sizes[3];               // K*K = 4096
  int HW = in_sizes[0] / (3 * B);      // 262144  (kernels assume K==64)
  const int GX = 256;                  // k_pix blocks per b

  // ws layout (floats): partialS[B*nbs*256] | sums[B*256] | res_part[B*GX*2]
  //                     | flagp[B] ; then bytes: k0c[B*HW] if it fits
  auto floats_needed = [&](int nbs) -> size_t {
    return (size_t)B * nbs * 256 + (size_t)B * 256 + (size_t)B * GX * 2 + B;
  };
  int nbs = 128;
  bool use_cache = true;
  if (ws_size < floats_needed(128) * 4 + (size_t)B * HW) {
    if (ws_size >= floats_needed(32) * 4 + (size_t)B * HW) nbs = 32;
    else { nbs = 32; use_cache = false; }
  }
  float* partialS = (float*)d_ws;
  float* sums = partialS + (size_t)B * nbs * 256;
  float* res_part = sums + (size_t)B * 256;
  int* flagp = (int*)(res_part + (size_t)B * GX * 2);
  unsigned char* k0c = use_cache ? (unsigned char*)(flagp + B) : nullptr;

  k_stats<<<dim3(nbs, B), 256, 0, stream>>>(pred, targ, pal, partialS, k0c, HW);
  k_reduce<<<B, 256, 0, stream>>>(partialS, dw, ndw, nbs, sums, flagp, B);
  if (use_cache)
    k_pix<true><<<dim3(GX, B), 256, 0, stream>>>(pred, targ, k0c, pal, nb, dw,
                                                 sums, flagp, res_part, HW, B);
  else
    k_pix<false><<<dim3(GX, B), 256, 0, stream>>>(pred, targ, k0c, pal, nb, dw,
                                                  sums, flagp, res_part, HW, B);
  k_final<<<1, 256, 0, stream>>>(sums, pal, nb, dw, res_part, GX,
                                 (float*)d_out, B, HW);
}